// Round 1
// baseline (3460.759 us; speedup 1.0000x reference)
//
#include <hip/hip_runtime.h>
#include <hip/hip_bf16.h>
#include <cstdint>

#define D_MODEL 1024
#define RANK 128
#define K_RANK_ 128
#define N_KNOW 32768
#define COARSE_K 64
#define FINE_K 16
#define NTOK 4096

using u32 = unsigned int;
using u64 = unsigned long long;

__device__ __forceinline__ u32 ordf(float v) {
    u32 u = __float_as_uint(v);
    return (u & 0x80000000u) ? ~u : (u | 0x80000000u);
}

// ---------------------------------------------------------------------------
// K1: stripe GEMM  C[m, n] = sum_k A[m,k] * B[k, col0+n]
//     A = x [NTOK, 1024] row-major, B = W_router [1024, 32768] row-major,
//     C = stripe logits [NTOK, SC] row-major (stripe-local columns).
// 128x128 tile, BK=16, 256 threads, 8x8 micro-tile, f32 FMA (no fp32 MFMA).
// ---------------------------------------------------------------------------
__global__ __launch_bounds__(256)
void k1_gemm(const float* __restrict__ A, const float* __restrict__ B,
             float* __restrict__ C, int col0, int SC)
{
    __shared__ float As[16][132];   // [k][m] transposed, padded
    __shared__ float Bs[16][132];   // [k][n] padded

    const int tid = threadIdx.x;
    const int bm = blockIdx.y * 128;
    const int bn = blockIdx.x * 128;
    const int tx = tid & 15, ty = tid >> 4;

    const int arow = tid >> 2;          // 0..63
    const int aq   = (tid & 3) << 2;    // k offset 0,4,8,12
    const int bcol = (tid & 31) << 2;   // 0..124
    const int brow = tid >> 5;          // 0..7

    float acc[8][8];
#pragma unroll
    for (int i = 0; i < 8; ++i)
#pragma unroll
        for (int j = 0; j < 8; ++j) acc[i][j] = 0.f;

    const float* Ap0 = A + (size_t)(bm + arow) * D_MODEL + aq;
    const float* Ap1 = Ap0 + (size_t)64 * D_MODEL;
    const float* Bp0 = B + (size_t)brow * N_KNOW + col0 + bn + bcol;
    const float* Bp1 = Bp0 + (size_t)8 * N_KNOW;

    for (int kb = 0; kb < D_MODEL; kb += 16) {
        float4 a0 = *(const float4*)(Ap0 + kb);
        float4 a1 = *(const float4*)(Ap1 + kb);
        float4 b0 = *(const float4*)(Bp0 + (size_t)kb * N_KNOW);
        float4 b1 = *(const float4*)(Bp1 + (size_t)kb * N_KNOW);
        if (kb) __syncthreads();
        As[aq + 0][arow] = a0.x; As[aq + 1][arow] = a0.y;
        As[aq + 2][arow] = a0.z; As[aq + 3][arow] = a0.w;
        As[aq + 0][arow + 64] = a1.x; As[aq + 1][arow + 64] = a1.y;
        As[aq + 2][arow + 64] = a1.z; As[aq + 3][arow + 64] = a1.w;
        *(float4*)&Bs[brow][bcol]     = b0;
        *(float4*)&Bs[brow + 8][bcol] = b1;
        __syncthreads();
#pragma unroll
        for (int kk = 0; kk < 16; ++kk) {
            float av[8], bv[8];
            *(float4*)&av[0] = *(const float4*)&As[kk][ty * 8];
            *(float4*)&av[4] = *(const float4*)&As[kk][ty * 8 + 4];
            *(float4*)&bv[0] = *(const float4*)&Bs[kk][tx * 8];
            *(float4*)&bv[4] = *(const float4*)&Bs[kk][tx * 8 + 4];
#pragma unroll
            for (int i = 0; i < 8; ++i)
#pragma unroll
                for (int j = 0; j < 8; ++j)
                    acc[i][j] = fmaf(av[i], bv[j], acc[i][j]);
        }
    }

#pragma unroll
    for (int i = 0; i < 8; ++i) {
        float* cp = C + (size_t)(bm + ty * 8 + i) * SC + bn + tx * 8;
        *(float4*)cp       = make_float4(acc[i][0], acc[i][1], acc[i][2], acc[i][3]);
        *(float4*)(cp + 4) = make_float4(acc[i][4], acc[i][5], acc[i][6], acc[i][7]);
    }
}

// ---------------------------------------------------------------------------
// K2: per-token running top-64 merge for one stripe.
// Key = (ord(value) << 32) | (N_KNOW-1 - global_col)  -> u64 max order matches
// jax top_k (desc value, lower index wins ties). Stripe 0: bisection threshold
// on ord space; later stripes: threshold = running 64th key. Compact survivors
// to LDS, exact rank-by-counting select writes sorted top-64 back to R.
// ---------------------------------------------------------------------------
template <int VPT>
__global__ __launch_bounds__(256)
void k2_topk(const float* __restrict__ L, u64* __restrict__ R,
             int col0, int stripe)
{
    constexpr int SC = VPT * 256;
    const int tt = blockIdx.x;
    const int tid = threadIdx.x;

    __shared__ u64 buf[4160];
    __shared__ int scnt;
    __shared__ int sred[4];

    u64 key[VPT];
    const float* row = L + (size_t)tt * SC;
#pragma unroll
    for (int j = 0; j < VPT; ++j) {
        int c = (j << 8) + tid;
        float v = row[c];
        key[j] = ((u64)ordf(v) << 32) | (u32)(N_KNOW - 1 - (col0 + c));
    }

    u64 tkey;
    if (stripe == 0) {
        u32 lo = 0, hi = 0xFFFFFFFFu;
        for (int it = 0; it < 28; ++it) {
            if (hi - lo <= 1) break;
            u32 mid = lo + ((hi - lo) >> 1);
            int c = 0;
#pragma unroll
            for (int j = 0; j < VPT; ++j) c += ((u32)(key[j] >> 32) > mid) ? 1 : 0;
#pragma unroll
            for (int o = 32; o; o >>= 1) c += __shfl_xor(c, o);
            if ((tid & 63) == 0) sred[tid >> 6] = c;
            __syncthreads();
            c = sred[0] + sred[1] + sred[2] + sred[3];
            __syncthreads();
            if (c >= COARSE_K) { lo = mid; if (c <= 768) break; }
            else hi = mid;
        }
        tkey = ((u64)lo << 32) | 0xFFFFFFFFull;   // key > tkey  <=>  ord > lo
        if (tid == 0) scnt = 0;
    } else {
        tkey = R[(size_t)tt * COARSE_K + 63];
        if (tid < COARSE_K) buf[tid] = R[(size_t)tt * COARSE_K + tid];
        if (tid == 0) scnt = COARSE_K;
    }
    __syncthreads();

#pragma unroll
    for (int j = 0; j < VPT; ++j)
        if (key[j] > tkey) buf[atomicAdd(&scnt, 1)] = key[j];
    __syncthreads();

    const int n = scnt;   // >= 64 by construction
    for (int i = tid; i < n; i += 256) {
        u64 ki = buf[i];
        int r = 0;
        for (int j = 0; j < n; ++j) r += (buf[j] > ki) ? 1 : 0;
        if (r < COARSE_K) R[(size_t)tt * COARSE_K + r] = ki;
    }
}

// ---------------------------------------------------------------------------
// K3: per-token fine stage. query = h @ W_q^T; 64 fine dots; wave-rank top-16;
// softmax; float4 weighted V combine.
// ---------------------------------------------------------------------------
__global__ __launch_bounds__(256)
void k3_fine(const float* __restrict__ h, const float* __restrict__ Wq,
             const float* __restrict__ Kall, const float* __restrict__ Vall,
             const u64* __restrict__ R, float* __restrict__ out)
{
    const int tt = blockIdx.x;
    const int tid = threadIdx.x;

    __shared__ float hrow[RANK];
    __shared__ float q[K_RANK_];
    __shared__ int   cidx[COARSE_K];
    __shared__ float sc[COARSE_K];
    __shared__ int   selg[FINE_K];
    __shared__ float selsc[FINE_K];
    __shared__ float w[FINE_K];

    if (tid < RANK) hrow[tid] = h[(size_t)tt * RANK + tid];
    if (tid < COARSE_K) {
        u64 k = R[(size_t)tt * COARSE_K + tid];
        cidx[tid] = (N_KNOW - 1) - (int)(u32)(k & 0xFFFFFFFFu);
    }
    __syncthreads();

    if (tid < K_RANK_) {
        float s = 0.f;
        const float* wr = Wq + (size_t)tid * RANK;
#pragma unroll 8
        for (int r = 0; r < RANK; ++r) s = fmaf(hrow[r], wr[r], s);
        q[tid] = s;
    }
    __syncthreads();

    {   // fine scores: 4 threads per candidate
        int c = tid >> 2, part = tid & 3;
        const float* kr = Kall + (size_t)cidx[c] * K_RANK_ + part * 32;
        const float* qp = q + part * 32;
        float s = 0.f;
#pragma unroll 8
        for (int r = 0; r < 32; ++r) s = fmaf(qp[r], kr[r], s);
        s += __shfl_xor(s, 1, 4);
        s += __shfl_xor(s, 2, 4);
        if (part == 0) sc[c] = s * 0.08838834764831845f;  // 1/sqrt(128)
    }
    __syncthreads();

    if (tid < COARSE_K) {   // wave 0: rank-by-counting top-16
        float v = sc[tid];
        u64 k = ((u64)ordf(v) << 32) | (u32)(63 - tid);
        int r = 0;
        for (int j = 0; j < 64; ++j) {
            u64 kj = __shfl(k, j);
            r += (kj > k) ? 1 : 0;
        }
        if (r < FINE_K) { selg[r] = cidx[tid]; selsc[r] = v; }
    }
    __syncthreads();

    if (tid < FINE_K) {
        float e = expf(selsc[tid] - selsc[0]);   // selsc[0] is the max
        float s = e;
        s += __shfl_xor(s, 1, 16);
        s += __shfl_xor(s, 2, 16);
        s += __shfl_xor(s, 4, 16);
        s += __shfl_xor(s, 8, 16);
        w[tid] = e / s;
    }
    __syncthreads();

    float4 o = make_float4(0.f, 0.f, 0.f, 0.f);
#pragma unroll
    for (int f = 0; f < FINE_K; ++f) {
        float wf = w[f];
        const float4 vv = *(const float4*)(Vall + (size_t)selg[f] * D_MODEL + tid * 4);
        o.x = fmaf(wf, vv.x, o.x);
        o.y = fmaf(wf, vv.y, o.y);
        o.z = fmaf(wf, vv.z, o.z);
        o.w = fmaf(wf, vv.w, o.w);
    }
    *(float4*)(out + (size_t)tt * D_MODEL + tid * 4) = o;
}

// ---------------------------------------------------------------------------
extern "C" void kernel_launch(void* const* d_in, const int* in_sizes, int n_in,
                              void* d_out, int out_size, void* d_ws, size_t ws_size,
                              hipStream_t stream)
{
    const float* x  = (const float*)d_in[0];
    const float* h  = (const float*)d_in[1];
    const float* Wr = (const float*)d_in[2];
    const float* Wq = (const float*)d_in[3];
    const float* Ka = (const float*)d_in[4];
    const float* Va = (const float*)d_in[5];
    float* out = (float*)d_out;

    // pick largest stripe width that fits ws: logits stripe + top64 state
    int SC = 4096;
    while (SC > 512 &&
           (size_t)NTOK * SC * 4 + (size_t)NTOK * COARSE_K * 8 > ws_size)
        SC >>= 1;

    float* Lbuf = (float*)d_ws;
    u64* R = (u64*)((char*)d_ws + (size_t)NTOK * SC * 4);

    const int nstripe = N_KNOW / SC;
    for (int s = 0; s < nstripe; ++s) {
        k1_gemm<<<dim3(SC / 128, NTOK / 128), 256, 0, stream>>>(x, Wr, Lbuf, s * SC, SC);
        switch (SC) {
            case 4096: k2_topk<16><<<NTOK, 256, 0, stream>>>(Lbuf, R, s * SC, s); break;
            case 2048: k2_topk< 8><<<NTOK, 256, 0, stream>>>(Lbuf, R, s * SC, s); break;
            case 1024: k2_topk< 4><<<NTOK, 256, 0, stream>>>(Lbuf, R, s * SC, s); break;
            default:   k2_topk< 2><<<NTOK, 256, 0, stream>>>(Lbuf, R, s * SC, s); break;
        }
    }
    k3_fine<<<NTOK, 256, 0, stream>>>(h, Wq, Ka, Va, R, out);
}

// Round 2
// 1195.878 us; speedup vs baseline: 2.8939x; 2.8939x over previous
//
#include <hip/hip_runtime.h>
#include <cstdint>

#define D_MODEL 1024
#define RANK 128
#define K_RANK_ 128
#define N_KNOW 32768
#define COARSE_K 64
#define FINE_K 16
#define NTOK 4096
#define MSEL 96
#define DELTA 2e-4f

using u32 = unsigned int;
using u64 = unsigned long long;
typedef __attribute__((ext_vector_type(8))) short short8v;
typedef __attribute__((ext_vector_type(4))) float f32x4;

__device__ __forceinline__ u32 ordf(float v) {
    u32 u = __float_as_uint(v);
    return (u & 0x80000000u) ? ~u : (u | 0x80000000u);
}
__device__ __forceinline__ float unordf(u32 o) {
    return (o & 0x80000000u) ? __uint_as_float(o ^ 0x80000000u)
                             : __uint_as_float(~o);
}
__device__ __forceinline__ ushort bf16rn(float f) {
    u32 u = __float_as_uint(f);
    u32 r = (u + 0x7FFFu + ((u >> 16) & 1u)) >> 16;
    return (ushort)r;
}
__device__ __forceinline__ float bf16tof(ushort h) {
    return __uint_as_float(((u32)h) << 16);
}
__device__ __forceinline__ void gload16(const void* g, void* l) {
    __builtin_amdgcn_global_load_lds(
        (const __attribute__((address_space(1))) char*)g,
        (__attribute__((address_space(3))) char*)l, 16, 0, 0);
}

// ---------------------------------------------------------------------------
// split x -> xhi/xlo bf16 (same [4096][1024] layout), float4 vectorized
// ---------------------------------------------------------------------------
__global__ __launch_bounds__(256)
void ksplit_x(const float* __restrict__ in, ushort* __restrict__ hi,
              ushort* __restrict__ lo)
{
    int i = blockIdx.x * 256 + threadIdx.x;
    float4 v = ((const float4*)in)[i];
    ushort h0 = bf16rn(v.x), h1 = bf16rn(v.y), h2 = bf16rn(v.z), h3 = bf16rn(v.w);
    ushort l0 = bf16rn(v.x - bf16tof(h0));
    ushort l1 = bf16rn(v.y - bf16tof(h1));
    ushort l2 = bf16rn(v.z - bf16tof(h2));
    ushort l3 = bf16rn(v.w - bf16tof(h3));
    ((ushort4*)hi)[i] = make_ushort4(h0, h1, h2, h3);
    ((ushort4*)lo)[i] = make_ushort4(l0, l1, l2, l3);
}

// ---------------------------------------------------------------------------
// split + transpose one W chunk: W[k][col0+n] (f32) -> wthi/wtlo [n][k] bf16
// ---------------------------------------------------------------------------
__global__ __launch_bounds__(256)
void ksplit_wt(const float* __restrict__ W, ushort* __restrict__ thi,
               ushort* __restrict__ tlo, int col0)
{
    __shared__ float tile[32][33];
    const int nb = blockIdx.x * 32;           // chunk-local n base
    const int kb = blockIdx.y * 32;           // k base
    const int tx = threadIdx.x & 31, ty = threadIdx.x >> 5;  // 32 x 8
#pragma unroll
    for (int q = 0; q < 4; ++q)
        tile[ty + q * 8][tx] = W[(size_t)(kb + ty + q * 8) * N_KNOW + col0 + nb + tx];
    __syncthreads();
#pragma unroll
    for (int q = 0; q < 4; ++q) {
        float v = tile[tx][ty + q * 8];       // = W[kb+tx][col0+nb+ty+q*8]
        ushort hh = bf16rn(v);
        ushort ll = bf16rn(v - bf16tof(hh));
        size_t o = (size_t)(nb + ty + q * 8) * D_MODEL + kb + tx;
        thi[o] = hh;
        tlo[o] = ll;
    }
}

// ---------------------------------------------------------------------------
// K1: bf16x2 split MFMA GEMM, 128x128 tile, BK=32, 4 waves, dbuf LDS,
// global_load_lds width 16. C[m][n] (f32, stripe-local cols) =
// xhi*whi + xhi*wlo + xlo*whi.
// ---------------------------------------------------------------------------
__global__ __launch_bounds__(256)
void k1_mfma(const ushort* __restrict__ xhi, const ushort* __restrict__ xlo,
             const ushort* __restrict__ wthi, const ushort* __restrict__ wtlo,
             float* __restrict__ C, int SC)
{
    __shared__ ushort lds[2][16384];   // [buf][Ahi|Alo|Bhi|Blo each 128x32]

    const int tid = threadIdx.x;
    const int bn = blockIdx.x * 128;
    const int bm = blockIdx.y * 128;
    const int lane = tid & 63;
    const int wv = tid >> 6;
    const int wr = wv >> 1, wc = wv & 1;
    const int lrow = lane & 15, lk = (lane >> 4) * 8;

    // staging sources: thread t, chunk i -> 16B; arr = i>>1 (0:Ahi 1:Alo 2:Bhi 3:Blo)
    const ushort* gsrc[8];
#pragma unroll
    for (int i = 0; i < 8; ++i) {
        const int arr = i >> 1;
        const int o = tid + ((i & 1) << 8);      // 0..511
        const int row = o >> 2;                  // 0..127
        const int kp = (o & 3) << 3;             // 0,8,16,24 (bf16 units)
        const ushort* base = (arr == 0) ? xhi : (arr == 1) ? xlo
                           : (arr == 2) ? wthi : wtlo;
        const int grow = (arr < 2) ? (bm + row) : (bn + row);
        gsrc[i] = base + (size_t)grow * D_MODEL + kp;
    }

    int aoff[4], boff[4];
#pragma unroll
    for (int m = 0; m < 4; ++m) aoff[m] = (wr * 64 + m * 16 + lrow) * 32 + lk;
#pragma unroll
    for (int n = 0; n < 4; ++n) boff[n] = (wc * 64 + n * 16 + lrow) * 32 + lk;

    f32x4 acc[4][4];
#pragma unroll
    for (int m = 0; m < 4; ++m)
#pragma unroll
        for (int n = 0; n < 4; ++n) acc[m][n] = (f32x4)(0.f);

#pragma unroll
    for (int i = 0; i < 8; ++i)
        gload16(gsrc[i], &lds[0][(tid + (i << 8)) * 8]);

    const int NKB = D_MODEL / 32;
    for (int kb = 0; kb < NKB; ++kb) {
        const int cur = kb & 1;
        __syncthreads();                    // drains vmcnt -> tile kb ready
        if (kb + 1 < NKB) {
#pragma unroll
            for (int i = 0; i < 8; ++i)
                gload16(gsrc[i] + (kb + 1) * 32,
                        &lds[cur ^ 1][(tid + (i << 8)) * 8]);
        }
        const ushort* lb = lds[cur];
        short8v ah[4], al[4], bh[4], bl[4];
#pragma unroll
        for (int m = 0; m < 4; ++m) {
            ah[m] = *(const short8v*)(lb + aoff[m]);
            al[m] = *(const short8v*)(lb + 4096 + aoff[m]);
        }
#pragma unroll
        for (int n = 0; n < 4; ++n) {
            bh[n] = *(const short8v*)(lb + 8192 + boff[n]);
            bl[n] = *(const short8v*)(lb + 12288 + boff[n]);
        }
#pragma unroll
        for (int m = 0; m < 4; ++m)
#pragma unroll
            for (int n = 0; n < 4; ++n) {
                acc[m][n] = __builtin_amdgcn_mfma_f32_16x16x32_bf16(ah[m], bh[n], acc[m][n], 0, 0, 0);
                acc[m][n] = __builtin_amdgcn_mfma_f32_16x16x32_bf16(ah[m], bl[n], acc[m][n], 0, 0, 0);
                acc[m][n] = __builtin_amdgcn_mfma_f32_16x16x32_bf16(al[m], bh[n], acc[m][n], 0, 0, 0);
            }
    }

    const int crow = bm + wr * 64 + (lane >> 4) * 4;
    const int ccol = bn + wc * 64 + lrow;
#pragma unroll
    for (int m = 0; m < 4; ++m)
#pragma unroll
        for (int n = 0; n < 4; ++n) {
#pragma unroll
            for (int r = 0; r < 4; ++r)
                C[(size_t)(crow + m * 16 + r) * SC + ccol + n * 16] = acc[m][n][r];
        }
}

// ---------------------------------------------------------------------------
// K2: per-token running top-M merge for one stripe (keys: ord(score)|~idx)
// ---------------------------------------------------------------------------
template <int M, int VPT>
__global__ __launch_bounds__(256)
void k2_topk(const float* __restrict__ L, u64* __restrict__ R,
             int col0, int stripe)
{
    constexpr int SC = VPT * 256;
    const int tt = blockIdx.x;
    const int tid = threadIdx.x;

    __shared__ u64 buf[4160];
    __shared__ int scnt;
    __shared__ int sred[4];

    u64 key[VPT];
    const float* row = L + (size_t)tt * SC;
#pragma unroll
    for (int j = 0; j < VPT; ++j) {
        int c = (j << 8) + tid;
        float v = row[c];
        key[j] = ((u64)ordf(v) << 32) | (u32)(N_KNOW - 1 - (col0 + c));
    }

    u64 tkey;
    if (stripe == 0) {
        u32 lo = 0, hi = 0xFFFFFFFFu;
        for (int it = 0; it < 28; ++it) {
            if (hi - lo <= 1) break;
            u32 mid = lo + ((hi - lo) >> 1);
            int c = 0;
#pragma unroll
            for (int j = 0; j < VPT; ++j) c += ((u32)(key[j] >> 32) > mid) ? 1 : 0;
#pragma unroll
            for (int o = 32; o; o >>= 1) c += __shfl_xor(c, o);
            if ((tid & 63) == 0) sred[tid >> 6] = c;
            __syncthreads();
            c = sred[0] + sred[1] + sred[2] + sred[3];
            __syncthreads();
            if (c >= M) { lo = mid; if (c <= 768) break; }
            else hi = mid;
        }
        tkey = ((u64)lo << 32) | 0xFFFFFFFFull;
        if (tid == 0) scnt = 0;
    } else {
        tkey = R[(size_t)tt * M + (M - 1)];
        if (tid < M) buf[tid] = R[(size_t)tt * M + tid];
        if (tid == 0) scnt = M;
    }
    __syncthreads();

#pragma unroll
    for (int j = 0; j < VPT; ++j)
        if (key[j] > tkey) buf[atomicAdd(&scnt, 1)] = key[j];
    __syncthreads();

    const int n = scnt;
    for (int i = tid; i < n; i += 256) {
        u64 ki = buf[i];
        int r = 0;
        for (int j = 0; j < n; ++j) r += (buf[j] > ki) ? 1 : 0;
        if (r < M) R[(size_t)tt * M + r] = ki;
    }
}

// ---------------------------------------------------------------------------
// K2b: repair — exact f32 re-score of candidates within DELTA of approx 64th
// score; writes final exact top-64 set to R64.
// ---------------------------------------------------------------------------
__global__ __launch_bounds__(256)
void k2b_repair(const u64* __restrict__ R96, const float* __restrict__ x,
                const float* __restrict__ W, u64* __restrict__ R64)
{
    const int tt = blockIdx.x;
    const int tid = threadIdx.x;

    __shared__ u64 keys[MSEL];
    __shared__ float s[MSEL];
    __shared__ u64 nk[MSEL];
    __shared__ float xrow[D_MODEL];
    __shared__ float red[4];
    __shared__ int slo, shi;

    if (tid < MSEL) {
        keys[tid] = R96[(size_t)tt * MSEL + tid];
        s[tid] = unordf((u32)(keys[tid] >> 32));
    }
    __syncthreads();

    const float t = s[COARSE_K - 1];
    if (tid == 0) {
        int lo = 0; while (s[lo] > t + DELTA) ++lo;
        int hi = MSEL - 1; while (s[hi] < t - DELTA) --hi;
        slo = lo; shi = hi;
    }
    __syncthreads();
    const int lo = slo, hi = shi;

    if (lo == COARSE_K - 1 && hi == COARSE_K - 1) {   // no ambiguity (common)
        if (tid < COARSE_K) R64[(size_t)tt * COARSE_K + tid] = keys[tid];
        return;
    }

    for (int i = tid; i < D_MODEL; i += 256) xrow[i] = x[(size_t)tt * D_MODEL + i];
    __syncthreads();

    for (int j = lo; j <= hi; ++j) {
        int col = (N_KNOW - 1) - (int)(u32)(keys[j] & 0xFFFFFFFFu);
        float p = 0.f;
#pragma unroll
        for (int q = 0; q < 4; ++q) {
            int k = tid + q * 256;
            p = fmaf(xrow[k], W[(size_t)k * N_KNOW + col], p);
        }
#pragma unroll
        for (int o = 32; o; o >>= 1) p += __shfl_xor(p, o);
        if ((tid & 63) == 0) red[tid >> 6] = p;
        __syncthreads();
        if (tid == 0) {
            float e = red[0] + red[1] + red[2] + red[3];
            nk[j] = ((u64)ordf(e) << 32) | (keys[j] & 0xFFFFFFFFu);
        }
        __syncthreads();
    }

    if (tid < lo) R64[(size_t)tt * COARSE_K + tid] = keys[tid];
    const int m = COARSE_K - lo;
    if (tid >= lo && tid <= hi) {
        u64 me = nk[tid];
        int r = 0;
        for (int j = lo; j <= hi; ++j) r += (nk[j] > me) ? 1 : 0;
        if (r < m) R64[(size_t)tt * COARSE_K + lo + r] = keys[tid];
    }
}

// ---------------------------------------------------------------------------
// K3: per-token fine stage (unchanged from round 1).
// ---------------------------------------------------------------------------
__global__ __launch_bounds__(256)
void k3_fine(const float* __restrict__ h, const float* __restrict__ Wq,
             const float* __restrict__ Kall, const float* __restrict__ Vall,
             const u64* __restrict__ R, float* __restrict__ out)
{
    const int tt = blockIdx.x;
    const int tid = threadIdx.x;

    __shared__ float hrow[RANK];
    __shared__ float q[K_RANK_];
    __shared__ int   cidx[COARSE_K];
    __shared__ float sc[COARSE_K];
    __shared__ int   selg[FINE_K];
    __shared__ float selsc[FINE_K];
    __shared__ float w[FINE_K];

    if (tid < RANK) hrow[tid] = h[(size_t)tt * RANK + tid];
    if (tid < COARSE_K) {
        u64 k = R[(size_t)tt * COARSE_K + tid];
        cidx[tid] = (N_KNOW - 1) - (int)(u32)(k & 0xFFFFFFFFu);
    }
    __syncthreads();

    if (tid < K_RANK_) {
        float s = 0.f;
        const float* wr = Wq + (size_t)tid * RANK;
#pragma unroll 8
        for (int r = 0; r < RANK; ++r) s = fmaf(hrow[r], wr[r], s);
        q[tid] = s;
    }
    __syncthreads();

    {
        int c = tid >> 2, part = tid & 3;
        const float* kr = Kall + (size_t)cidx[c] * K_RANK_ + part * 32;
        const float* qp = q + part * 32;
        float s = 0.f;
#pragma unroll 8
        for (int r = 0; r < 32; ++r) s = fmaf(qp[r], kr[r], s);
        s += __shfl_xor(s, 1, 4);
        s += __shfl_xor(s, 2, 4);
        if (part == 0) sc[c] = s * 0.08838834764831845f;
    }
    __syncthreads();

    if (tid < COARSE_K) {
        float v = sc[tid];
        u64 k = ((u64)ordf(v) << 32) | (u32)(63 - tid);
        int r = 0;
        for (int j = 0; j < 64; ++j) {
            u64 kj = __shfl(k, j);
            r += (kj > k) ? 1 : 0;
        }
        if (r < FINE_K) { selg[r] = cidx[tid]; selsc[r] = v; }
    }
    __syncthreads();

    if (tid < FINE_K) {
        float e = expf(selsc[tid] - selsc[0]);
        float ssum = e;
        ssum += __shfl_xor(ssum, 1, 16);
        ssum += __shfl_xor(ssum, 2, 16);
        ssum += __shfl_xor(ssum, 4, 16);
        ssum += __shfl_xor(ssum, 8, 16);
        w[tid] = e / ssum;
    }
    __syncthreads();

    float4 o = make_float4(0.f, 0.f, 0.f, 0.f);
#pragma unroll
    for (int f = 0; f < FINE_K; ++f) {
        float wf = w[f];
        const float4 vv = *(const float4*)(Vall + (size_t)selg[f] * D_MODEL + tid * 4);
        o.x = fmaf(wf, vv.x, o.x);
        o.y = fmaf(wf, vv.y, o.y);
        o.z = fmaf(wf, vv.z, o.z);
        o.w = fmaf(wf, vv.w, o.w);
    }
    *(float4*)(out + (size_t)tt * D_MODEL + tid * 4) = o;
}

// ---------------------------------------------------------------------------
extern "C" void kernel_launch(void* const* d_in, const int* in_sizes, int n_in,
                              void* d_out, int out_size, void* d_ws, size_t ws_size,
                              hipStream_t stream)
{
    const float* x  = (const float*)d_in[0];
    const float* h  = (const float*)d_in[1];
    const float* Wr = (const float*)d_in[2];
    const float* Wq = (const float*)d_in[3];
    const float* Ka = (const float*)d_in[4];
    const float* Va = (const float*)d_in[5];
    float* out = (float*)d_out;

    const size_t XSP  = (size_t)NTOK * D_MODEL * 2;
    const size_t R96B = (size_t)NTOK * MSEL * 8;
    const size_t R64B = (size_t)NTOK * COARSE_K * 8;

    int SC = 4096;
    while (SC > 512) {
        size_t need = (size_t)SC * D_MODEL * 4      // wthi+wtlo chunk
                    + 2 * XSP + R96B + R64B
                    + (size_t)NTOK * SC * 4;        // logits stripe
        if (need <= ws_size) break;
        SC >>= 1;
    }

    char* p = (char*)d_ws;
    ushort* wthi = (ushort*)p; p += (size_t)SC * D_MODEL * 2;
    ushort* wtlo = (ushort*)p; p += (size_t)SC * D_MODEL * 2;
    ushort* xhi  = (ushort*)p; p += XSP;
    ushort* xlo  = (ushort*)p; p += XSP;
    float*  L    = (float*)p;  p += (size_t)NTOK * SC * 4;
    u64*    R96  = (u64*)p;    p += R96B;
    u64*    R64  = (u64*)p;

    ksplit_x<<<NTOK * D_MODEL / 4 / 256, 256, 0, stream>>>(x, xhi, xlo);

    const int nstripe = N_KNOW / SC;
    for (int s = 0; s < nstripe; ++s) {
        ksplit_wt<<<dim3(SC / 32, D_MODEL / 32), 256, 0, stream>>>(Wr, wthi, wtlo, s * SC);
        k1_mfma<<<dim3(SC / 128, NTOK / 128), 256, 0, stream>>>(xhi, xlo, wthi, wtlo, L, SC);
        switch (SC) {
            case 4096: k2_topk<MSEL, 16><<<NTOK, 256, 0, stream>>>(L, R96, s * SC, s); break;
            case 2048: k2_topk<MSEL,  8><<<NTOK, 256, 0, stream>>>(L, R96, s * SC, s); break;
            case 1024: k2_topk<MSEL,  4><<<NTOK, 256, 0, stream>>>(L, R96, s * SC, s); break;
            default:   k2_topk<MSEL,  2><<<NTOK, 256, 0, stream>>>(L, R96, s * SC, s); break;
        }
    }
    k2b_repair<<<NTOK, 256, 0, stream>>>(R96, x, Wr, R64);
    k3_fine<<<NTOK, 256, 0, stream>>>(h, Wq, Ka, Va, R64, out);
}